// Round 20
// baseline (47.690 us; speedup 1.0000x reference)
//
#include <hip/hip_runtime.h>

// LVAE_shGLM encoder, fused bf16-MFMA implementation for gfx950.
// Round 20: intra-block dual-stream pipeline on the r18 base (best, 40.2us).
// r19 swizzle null -> conflicts not critical; surviving theory is phase-
// latency exposure (r11-vs-r14: co-residency worth 12us; r18: stream-work
// worth 2.5us). BT=128 split into H0/H1 with separate 33KB h-buffers:
//   S1 GEMM1(H0) | S2 GEMM3(H0) ∥ GEMM1(H1) fused-kt | epi(A,B)
//   S3 GEMM3(H1) ∥ mu2(H1)[w0-3] ∥ mu4(H0)[w4-7] | epi(B) | S4 mu4(H1)
// Two independent MFMA/load streams per barrier segment double the work
// hiding each load's latency. All frag/epi/mu formulas byte-identical to
// verified r18. S2 regs: accP+accQ=64 AGPR + ~55 arch (unroll 2 caps
// hoisting, r15-proven). Gates: WRITE 7.8MB (spill), VGPR<=60, Occ~27%.
//
//   h_mid  = relu(windows @ W1 + b1)   windows[t,k] = pad[t+k]
//   mu_mid = h_mid @ W2 + b2           -> out[:, 0:4]
//   h_leaf = relu(h_mid @ Wl1 + bl1)
//   mu_leaf= h_leaf @ Wl2 + bl2        -> out[:, 4:20]

typedef __bf16 bf16;
typedef __bf16 bf16x8 __attribute__((ext_vector_type(8)));
typedef __bf16 bf16x4 __attribute__((ext_vector_type(4)));
typedef float  f32x4  __attribute__((ext_vector_type(4)));
typedef float  f32x16 __attribute__((ext_vector_type(16)));

constexpr int T_DATA = 100000;
constexpr int T_V    = 100;
constexpr int WIN    = 199;   // 2*T_V - 1
constexpr int HID    = 256;
constexpr int BT     = 128;   // timesteps per block (two 64-t halves)
constexpr int CSTR   = 264;   // h-buffer row stride [t][ch]; 528B, 16B-aligned
constexpr int VLEN   = 352;   // window span: 128 t + 207 max k + 8 frag + pad
constexpr int VSTR   = 360;   // Vdup row stride (720B, 16B-aligned)

// ws layout in bf16 elements (identical to r10-r19, byte-for-byte):
//   [0*512     ..) PW1   13 kt(K=16) x 8 mt(32 ch) = 104 groups (k>=199 zeroed)
//   [104*512   ..) PWL1  16 kt x 8 mt              = 128 groups
//   [232*512   ..) PW2   8 kt(K=32), 16x16 frag, ch 0..3 real
//   [240*512   ..) PWL2  8 kt(K=32), 16x16 frag, 16 ch
constexpr int PWL1_OFF = 104 * 512;
constexpr int PW2_OFF  = 232 * 512;
constexpr int PWL2_OFF = 240 * 512;   // total 248 KB <= ws

__global__ void pack_weights(const float* __restrict__ W1, const float* __restrict__ W2,
                             const float* __restrict__ Wl1, const float* __restrict__ Wl2,
                             bf16* __restrict__ ws) {
  const int gid  = blockIdx.x * blockDim.x + threadIdx.x;  // [0, 15872)
  const int lane = gid & 63;
  const int grp  = gid >> 6;        // [0, 248)
  bf16x8 v;
  if (grp < 104) {                  // PW1: lane(row)=ch, k=(lane>>5)*8+j
    const int kt = grp >> 3, nt = grp & 7, n = nt * 32 + (lane & 31);
#pragma unroll
    for (int j = 0; j < 8; ++j) {
      const int k = kt * 16 + (lane >> 5) * 8 + j;
      v[j] = (k < WIN) ? (bf16)W1[k * HID + n] : (bf16)0.0f;
    }
  } else if (grp < 232) {           // PWL1
    const int q = grp - 104;
    const int kt = q >> 3, nt = q & 7, n = nt * 32 + (lane & 31);
#pragma unroll
    for (int j = 0; j < 8; ++j) {
      const int k = kt * 16 + (lane >> 5) * 8 + j;
      v[j] = (bf16)Wl1[k * HID + n];
    }
  } else if (grp < 240) {           // PW2: 16x16 frag, ch 0..3 real
    const int kt = grp - 232, m = lane & 15;
#pragma unroll
    for (int j = 0; j < 8; ++j) {
      const int k = kt * 32 + (lane >> 4) * 8 + j;
      v[j] = (m < 4) ? (bf16)W2[k * 4 + m] : (bf16)0.0f;
    }
  } else {                          // PWL2
    const int kt = grp - 240, m = lane & 15;
#pragma unroll
    for (int j = 0; j < 8; ++j) {
      const int k = kt * 32 + (lane >> 4) * 8 + j;
      v[j] = (bf16)Wl2[k * 16 + m];
    }
  }
  *reinterpret_cast<bf16x8*>(ws + (size_t)gid * 8) = v;
}

__global__ __launch_bounds__(512, 4) void fused_enc(
    const float* __restrict__ V, const float* __restrict__ b1,
    const float* __restrict__ b2, const float* __restrict__ bl1,
    const float* __restrict__ bl2, const bf16* __restrict__ ws,
    float* __restrict__ out) {
  __shared__ bf16 Vdup[8][VSTR];     // 5.8 KB: Vdup[p][q] = pad[t0-99+q+p]
  __shared__ bf16 hbufA[64 * CSTR];  // 33 KB: H0's h (h_mid, then h_leaf)
  __shared__ bf16 hbufB[64 * CSTR];  // 33 KB: H1's h
  // total 73344 B -> 2 blocks/CU

  const int tid  = threadIdx.x;
  const int lane = tid & 63;
  const int w    = tid >> 6;            // wave id [0,8): owns 32-channel stripe w
  const int c5   = lane & 31;           // 32x32 frag row/col index
  const int hi   = lane >> 5;           // 32x32 frag k-half
  const int m    = lane & 15;           // 16x16 frag index
  const int g    = lane >> 4;           // 16x16 k-group
  const long t0  = (long)blockIdx.x * BT;

  // ---- stage 8 shifted bf16 window copies (covers both halves) ----
  for (int c = tid; c < 8 * VLEN; c += 512) {
    const int p = c / VLEN, q = c - p * VLEN;
    const long src = t0 + q + p - (T_V - 1);
    const float v = (src >= 0 && src < T_DATA) ? V[src] : 0.0f;
    Vdup[p][q] = (bf16)v;
  }
  __syncthreads();   // B0

  const int p  = lane & 7;
  const int qb = (c5 + hi * 8) - p;     // aligned B-frag base within Vdup row p
  const bf16* vrow = &Vdup[p][0];

  f32x16 accP[2], accQ[2];
#pragma unroll
  for (int nt = 0; nt < 2; ++nt) { accP[nt] = (f32x16){}; }

  // ---- S1: GEMM1(H0) -> accP ----
#pragma unroll
  for (int kt = 0; kt < 13; ++kt) {
    const bf16x8 a = *reinterpret_cast<const bf16x8*>(
        ws + (size_t)(kt * 8 + w) * 512 + lane * 8);
#pragma unroll
    for (int nt = 0; nt < 2; ++nt) {
      const bf16x8 b = *reinterpret_cast<const bf16x8*>(vrow + qb + nt * 32 + kt * 16);
      accP[nt] = __builtin_amdgcn_mfma_f32_32x32x16_bf16(a, b, accP[nt], 0, 0, 0);
    }
  }

  // ---- epi: h_mid(H0) -> hbufA (packed b64; r18 formula, nt<2) ----
  {
    f32x4 bb[4];
#pragma unroll
    for (int q = 0; q < 4; ++q)
      bb[q] = *reinterpret_cast<const f32x4*>(&b1[w * 32 + 8 * q + 4 * hi]);
#pragma unroll
    for (int nt = 0; nt < 2; ++nt) {
      const int t = nt * 32 + c5;
#pragma unroll
      for (int q = 0; q < 4; ++q) {
        bf16x4 hv;
#pragma unroll
        for (int i = 0; i < 4; ++i)
          hv[i] = (bf16)fmaxf(accP[nt][4 * q + i] + bb[q][i], 0.0f);
        *reinterpret_cast<bf16x4*>(&hbufA[t * CSTR + w * 32 + 8 * q + 4 * hi]) = hv;
      }
    }
  }
  __syncthreads();   // B1: h_mid(H0) visible

  // ---- S2: GEMM3(H0) [accQ] ∥ GEMM1(H1) [accP reused] — fused kt loop ----
#pragma unroll
  for (int nt = 0; nt < 2; ++nt) { accP[nt] = (f32x16){}; accQ[nt] = (f32x16){}; }
#pragma unroll 2
  for (int kt = 0; kt < 13; ++kt) {
    const bf16x8 a3 = *reinterpret_cast<const bf16x8*>(
        ws + PWL1_OFF + (size_t)(kt * 8 + w) * 512 + lane * 8);
    const bf16x8 a1 = *reinterpret_cast<const bf16x8*>(
        ws + (size_t)(kt * 8 + w) * 512 + lane * 8);
    const int koff = kt * 16 + hi * 8;
#pragma unroll
    for (int nt = 0; nt < 2; ++nt) {
      const bf16x8 b3 = *reinterpret_cast<const bf16x8*>(
          &hbufA[(nt * 32 + c5) * CSTR + koff]);
      accQ[nt] = __builtin_amdgcn_mfma_f32_32x32x16_bf16(a3, b3, accQ[nt], 0, 0, 0);
      const bf16x8 b1f = *reinterpret_cast<const bf16x8*>(
          vrow + qb + 64 + nt * 32 + kt * 16);
      accP[nt] = __builtin_amdgcn_mfma_f32_32x32x16_bf16(a1, b1f, accP[nt], 0, 0, 0);
    }
  }
#pragma unroll
  for (int kt = 13; kt < 16; ++kt) {    // GEMM3(H0) tail
    const bf16x8 a3 = *reinterpret_cast<const bf16x8*>(
        ws + PWL1_OFF + (size_t)(kt * 8 + w) * 512 + lane * 8);
    const int koff = kt * 16 + hi * 8;
#pragma unroll
    for (int nt = 0; nt < 2; ++nt) {
      const bf16x8 b3 = *reinterpret_cast<const bf16x8*>(
          &hbufA[(nt * 32 + c5) * CSTR + koff]);
      accQ[nt] = __builtin_amdgcn_mfma_f32_32x32x16_bf16(a3, b3, accQ[nt], 0, 0, 0);
    }
  }
  // mu_mid(H0): waves 0-3, t-tile w (t = w*16+m in 0..63); reads h_mid(H0)
  if (w < 4) {
    f32x4 mu = {0.f, 0.f, 0.f, 0.f};
#pragma unroll
    for (int kt = 0; kt < 8; ++kt) {
      const bf16x8 a = *reinterpret_cast<const bf16x8*>(
          ws + PW2_OFF + (size_t)kt * 512 + lane * 8);
      const bf16x8 b = *reinterpret_cast<const bf16x8*>(
          &hbufA[(w * 16 + m) * CSTR + kt * 32 + g * 8]);
      mu = __builtin_amdgcn_mfma_f32_16x16x32_bf16(a, b, mu, 0, 0, 0);
    }
    const long t = t0 + w * 16 + m;     // D: col=t(m), row=ch g*4+j
    if (g == 0 && t < T_DATA) {
      const f32x4 b2v = *reinterpret_cast<const f32x4*>(b2);
      f32x4 o;
#pragma unroll
      for (int j = 0; j < 4; ++j) o[j] = mu[j] + b2v[j];
      *reinterpret_cast<f32x4*>(&out[t * 20]) = o;
    }
  }
  __syncthreads();   // B2: WAR on hbufA (all h_mid(H0) reads done)

  // ---- epi: h_leaf(H0)->hbufA (accQ), h_mid(H1)->hbufB (accP) ----
  {
    f32x4 bbL[4], bbM[4];
#pragma unroll
    for (int q = 0; q < 4; ++q) {
      bbL[q] = *reinterpret_cast<const f32x4*>(&bl1[w * 32 + 8 * q + 4 * hi]);
      bbM[q] = *reinterpret_cast<const f32x4*>(&b1[w * 32 + 8 * q + 4 * hi]);
    }
#pragma unroll
    for (int nt = 0; nt < 2; ++nt) {
      const int t = nt * 32 + c5;
#pragma unroll
      for (int q = 0; q < 4; ++q) {
        bf16x4 hvL, hvM;
#pragma unroll
        for (int i = 0; i < 4; ++i) {
          hvL[i] = (bf16)fmaxf(accQ[nt][4 * q + i] + bbL[q][i], 0.0f);
          hvM[i] = (bf16)fmaxf(accP[nt][4 * q + i] + bbM[q][i], 0.0f);
        }
        *reinterpret_cast<bf16x4*>(&hbufA[t * CSTR + w * 32 + 8 * q + 4 * hi]) = hvL;
        *reinterpret_cast<bf16x4*>(&hbufB[t * CSTR + w * 32 + 8 * q + 4 * hi]) = hvM;
      }
    }
  }
  __syncthreads();   // B3: h_leaf(H0) + h_mid(H1) visible

  // ---- S3: GEMM3(H1) [accQ reused] ∥ mu2(H1)[w0-3] ∥ mu4(H0)[w4-7] ----
#pragma unroll
  for (int nt = 0; nt < 2; ++nt) accQ[nt] = (f32x16){};
#pragma unroll 2
  for (int kt = 0; kt < 16; ++kt) {
    const bf16x8 a3 = *reinterpret_cast<const bf16x8*>(
        ws + PWL1_OFF + (size_t)(kt * 8 + w) * 512 + lane * 8);
    const int koff = kt * 16 + hi * 8;
#pragma unroll
    for (int nt = 0; nt < 2; ++nt) {
      const bf16x8 b3 = *reinterpret_cast<const bf16x8*>(
          &hbufB[(nt * 32 + c5) * CSTR + koff]);
      accQ[nt] = __builtin_amdgcn_mfma_f32_32x32x16_bf16(a3, b3, accQ[nt], 0, 0, 0);
    }
  }
  if (w < 4) {       // mu_mid(H1): t = 64 + w*16 + m, reads hbufB (h_mid H1)
    f32x4 mu = {0.f, 0.f, 0.f, 0.f};
#pragma unroll
    for (int kt = 0; kt < 8; ++kt) {
      const bf16x8 a = *reinterpret_cast<const bf16x8*>(
          ws + PW2_OFF + (size_t)kt * 512 + lane * 8);
      const bf16x8 b = *reinterpret_cast<const bf16x8*>(
          &hbufB[(w * 16 + m) * CSTR + kt * 32 + g * 8]);
      mu = __builtin_amdgcn_mfma_f32_16x16x32_bf16(a, b, mu, 0, 0, 0);
    }
    const long t = t0 + 64 + w * 16 + m;
    if (g == 0 && t < T_DATA) {
      const f32x4 b2v = *reinterpret_cast<const f32x4*>(b2);
      f32x4 o;
#pragma unroll
      for (int j = 0; j < 4; ++j) o[j] = mu[j] + b2v[j];
      *reinterpret_cast<f32x4*>(&out[t * 20]) = o;
    }
  } else {           // mu_leaf(H0): t = (w-4)*16 + m, reads hbufA (h_leaf H0)
    f32x4 mu = {0.f, 0.f, 0.f, 0.f};
#pragma unroll
    for (int kq = 0; kq < 8; ++kq) {
      const bf16x8 a = *reinterpret_cast<const bf16x8*>(
          ws + PWL2_OFF + (size_t)kq * 512 + lane * 8);
      const bf16x8 b = *reinterpret_cast<const bf16x8*>(
          &hbufA[((w - 4) * 16 + m) * CSTR + kq * 32 + g * 8]);
      mu = __builtin_amdgcn_mfma_f32_16x16x32_bf16(a, b, mu, 0, 0, 0);
    }
    const long t = t0 + (w - 4) * 16 + m;
    if (t < T_DATA) {
      const f32x4 blv = *reinterpret_cast<const f32x4*>(&bl2[g * 4]);
      f32x4 o;
#pragma unroll
      for (int j = 0; j < 4; ++j) o[j] = mu[j] + blv[j];
      *reinterpret_cast<f32x4*>(&out[t * 20 + 4 + g * 4]) = o;
    }
  }
  __syncthreads();   // B4: WAR on hbufB (all h_mid(H1) reads done)

  // ---- epi: h_leaf(H1) -> hbufB (accQ) ----
  {
    f32x4 bb[4];
#pragma unroll
    for (int q = 0; q < 4; ++q)
      bb[q] = *reinterpret_cast<const f32x4*>(&bl1[w * 32 + 8 * q + 4 * hi]);
#pragma unroll
    for (int nt = 0; nt < 2; ++nt) {
      const int t = nt * 32 + c5;
#pragma unroll
      for (int q = 0; q < 4; ++q) {
        bf16x4 hv;
#pragma unroll
        for (int i = 0; i < 4; ++i)
          hv[i] = (bf16)fmaxf(accQ[nt][4 * q + i] + bb[q][i], 0.0f);
        *reinterpret_cast<bf16x4*>(&hbufB[t * CSTR + w * 32 + 8 * q + 4 * hi]) = hv;
      }
    }
  }
  __syncthreads();   // B5: h_leaf(H1) visible

  // ---- S4: mu_leaf(H1): waves 4-7, t = 64 + (w-4)*16 + m ----
  if (w >= 4) {
    f32x4 mu = {0.f, 0.f, 0.f, 0.f};
#pragma unroll
    for (int kq = 0; kq < 8; ++kq) {
      const bf16x8 a = *reinterpret_cast<const bf16x8*>(
          ws + PWL2_OFF + (size_t)kq * 512 + lane * 8);
      const bf16x8 b = *reinterpret_cast<const bf16x8*>(
          &hbufB[((w - 4) * 16 + m) * CSTR + kq * 32 + g * 8]);
      mu = __builtin_amdgcn_mfma_f32_16x16x32_bf16(a, b, mu, 0, 0, 0);
    }
    const long t = t0 + 64 + (w - 4) * 16 + m;
    if (t < T_DATA) {
      const f32x4 blv = *reinterpret_cast<const f32x4*>(&bl2[g * 4]);
      f32x4 o;
#pragma unroll
      for (int j = 0; j < 4; ++j) o[j] = mu[j] + blv[j];
      *reinterpret_cast<f32x4*>(&out[t * 20 + 4 + g * 4]) = o;
    }
  }
}

extern "C" void kernel_launch(void* const* d_in, const int* in_sizes, int n_in,
                              void* d_out, int out_size, void* d_ws, size_t ws_size,
                              hipStream_t stream) {
  const float* V   = (const float*)d_in[0];
  const float* W1  = (const float*)d_in[1];
  const float* b1  = (const float*)d_in[2];
  const float* W2  = (const float*)d_in[3];
  const float* b2  = (const float*)d_in[4];
  const float* Wl1 = (const float*)d_in[5];
  const float* bl1 = (const float*)d_in[6];
  const float* Wl2 = (const float*)d_in[7];
  const float* bl2 = (const float*)d_in[8];
  bf16* ws = (bf16*)d_ws;   // needs 253952 bytes
  float* out = (float*)d_out;

  pack_weights<<<62, 256, 0, stream>>>(W1, W2, Wl1, Wl2, ws);

  const int grid = (T_DATA + BT - 1) / BT;   // 782
  fused_enc<<<grid, 512, 0, stream>>>(V, b1, b2, bl1, bl2, ws, out);
}

// Round 21
// 40.192 us; speedup vs baseline: 1.1866x; 1.1866x over previous
//
#include <hip/hip_runtime.h>

// LVAE_shGLM encoder, fused bf16-MFMA implementation for gfx950.
// Round 21: REVERT to r18 (session best, 40.23us, verified). r20's dual-stream
// regressed 10% (barriers 4->6, bank conflicts 1.35M->2.70M) — the last
// structural lever falsified. r18 = transposed compute (D = W^T x X^T with
// prepacked weights as the A operand), packed b64 LDS epilogues, dwordx4 mu
// stores, 4 barriers, 2 blocks/CU. Confirmed mechanisms captured here:
// instruction-stream reduction (r18, +2.5us) and 2-block co-residency
// (r11-vs-r14, ~12us). MFMA floor 10.3us; this structure's plateau ~37.5us.
//
//   h_mid  = relu(windows @ W1 + b1)   windows[t,k] = pad[t+k]
//   mu_mid = h_mid @ W2 + b2           -> out[:, 0:4]
//   h_leaf = relu(h_mid @ Wl1 + bl1)
//   mu_leaf= h_leaf @ Wl2 + bl2        -> out[:, 4:20]

typedef __bf16 bf16;
typedef __bf16 bf16x8 __attribute__((ext_vector_type(8)));
typedef __bf16 bf16x4 __attribute__((ext_vector_type(4)));
typedef float  f32x4  __attribute__((ext_vector_type(4)));
typedef float  f32x16 __attribute__((ext_vector_type(16)));

constexpr int T_DATA = 100000;
constexpr int T_V    = 100;
constexpr int WIN    = 199;   // 2*T_V - 1
constexpr int HID    = 256;
constexpr int BT     = 128;   // timesteps per block
constexpr int CSTR   = 264;   // hbuf row stride: [t][channel], 528B (16B-aligned)
constexpr int VLEN   = 352;   // window span: 128 t + 207 max k + 8 frag + pad
constexpr int VSTR   = 360;   // Vdup row stride (720B, 16B-aligned)

// ws layout in bf16 elements (identical to r10-r20, byte-for-byte):
//   [0*512     ..) PW1   13 kt(K=16) x 8 mt(32 ch) = 104 groups (k>=199 zeroed)
//   [104*512   ..) PWL1  16 kt x 8 mt              = 128 groups
//   [232*512   ..) PW2   8 kt(K=32), 16x16 frag, ch 0..3 real
//   [240*512   ..) PWL2  8 kt(K=32), 16x16 frag, 16 ch
// These groups serve as the A-operand (W^T) fragments — A-frag lane layout
// mirrors B-frag (row=lane&31, k=(lane>>5)*8+j), so the bytes serve both.
constexpr int PWL1_OFF = 104 * 512;
constexpr int PW2_OFF  = 232 * 512;
constexpr int PWL2_OFF = 240 * 512;   // total 248 KB <= ws

__global__ void pack_weights(const float* __restrict__ W1, const float* __restrict__ W2,
                             const float* __restrict__ Wl1, const float* __restrict__ Wl2,
                             bf16* __restrict__ ws) {
  const int gid  = blockIdx.x * blockDim.x + threadIdx.x;  // [0, 15872)
  const int lane = gid & 63;
  const int grp  = gid >> 6;        // [0, 248)
  bf16x8 v;
  if (grp < 104) {                  // PW1: lane(row)=ch, k=(lane>>5)*8+j
    const int kt = grp >> 3, nt = grp & 7, n = nt * 32 + (lane & 31);
#pragma unroll
    for (int j = 0; j < 8; ++j) {
      const int k = kt * 16 + (lane >> 5) * 8 + j;
      v[j] = (k < WIN) ? (bf16)W1[k * HID + n] : (bf16)0.0f;
    }
  } else if (grp < 232) {           // PWL1
    const int q = grp - 104;
    const int kt = q >> 3, nt = q & 7, n = nt * 32 + (lane & 31);
#pragma unroll
    for (int j = 0; j < 8; ++j) {
      const int k = kt * 16 + (lane >> 5) * 8 + j;
      v[j] = (bf16)Wl1[k * HID + n];
    }
  } else if (grp < 240) {           // PW2: 16x16 frag, ch 0..3 real
    const int kt = grp - 232, m = lane & 15;
#pragma unroll
    for (int j = 0; j < 8; ++j) {
      const int k = kt * 32 + (lane >> 4) * 8 + j;
      v[j] = (m < 4) ? (bf16)W2[k * 4 + m] : (bf16)0.0f;
    }
  } else {                          // PWL2
    const int kt = grp - 240, m = lane & 15;
#pragma unroll
    for (int j = 0; j < 8; ++j) {
      const int k = kt * 32 + (lane >> 4) * 8 + j;
      v[j] = (bf16)Wl2[k * 16 + m];
    }
  }
  *reinterpret_cast<bf16x8*>(ws + (size_t)gid * 8) = v;
}

__global__ __launch_bounds__(512, 4) void fused_enc(
    const float* __restrict__ V, const float* __restrict__ b1,
    const float* __restrict__ b2, const float* __restrict__ bl1,
    const float* __restrict__ bl2, const bf16* __restrict__ ws,
    float* __restrict__ out) {
  __shared__ bf16 Vdup[8][VSTR];    // 5.8 KB: Vdup[p][q] = pad[t0-99+q+p]
  __shared__ bf16 hbuf[BT * CSTR];  // 67.6 KB: H = h^T as [t][channel]
  // total 73344 B -> 2 blocks/CU

  const int tid  = threadIdx.x;
  const int lane = tid & 63;
  const int w    = tid >> 6;            // wave id [0,8): owns 32-channel stripe w
  const int c5   = lane & 31;           // 32x32 frag row/col index
  const int hi   = lane >> 5;           // 32x32 frag k-half
  const int m    = lane & 15;           // 16x16 frag index
  const int g    = lane >> 4;           // 16x16 k-group
  const long t0  = (long)blockIdx.x * BT;

  // ---- 1. stage 8 shifted bf16 window copies ----
  for (int c = tid; c < 8 * VLEN; c += 512) {
    const int p = c / VLEN, q = c - p * VLEN;
    const long src = t0 + q + p - (T_V - 1);
    const float v = (src >= 0 && src < T_DATA) ? V[src] : 0.0f;
    Vdup[p][q] = (bf16)v;
  }
  __syncthreads();   // B0

  // B-frag (windows as B): element s = (nt*32 + c5) + kt*16 + hi*8 + j;
  // s mod 8 = c5&7 = lane&7 (lane-constant) -> copy p gives one aligned b128.
  const int p  = lane & 7;
  const int qb = (c5 + hi * 8) - p;     // multiple of 8; 16B-aligned base
  const bf16* vrow = &Vdup[p][0];

  f32x16 acc[4];                        // [nt]: t-tiles nt*32..nt*32+31, ch stripe w
#pragma unroll
  for (int nt = 0; nt < 4; ++nt) acc[nt] = (f32x16){};

  // ---- 2. GEMM1: H1[ch][t] = W1^T (A, global prepack) x windows^T (B, LDS) ----
#pragma unroll
  for (int kt = 0; kt < 13; ++kt) {
    const bf16x8 a = *reinterpret_cast<const bf16x8*>(
        ws + (size_t)(kt * 8 + w) * 512 + lane * 8);
#pragma unroll
    for (int nt = 0; nt < 4; ++nt) {
      const bf16x8 b = *reinterpret_cast<const bf16x8*>(vrow + qb + nt * 32 + kt * 16);
      acc[nt] = __builtin_amdgcn_mfma_f32_32x32x16_bf16(a, b, acc[nt], 0, 0, 0);
    }
  }

  // ---- 3. h_mid epilogue: packed b64 writes. D: col=t (c5), row=channel =
  //      (r&3) + 8*(r>>2) + 4*hi -> r=4q+i covers 4 consecutive channels. ----
  {
    f32x4 bb[4];
#pragma unroll
    for (int q = 0; q < 4; ++q)
      bb[q] = *reinterpret_cast<const f32x4*>(&b1[w * 32 + 8 * q + 4 * hi]);
#pragma unroll
    for (int nt = 0; nt < 4; ++nt) {
      const int t = nt * 32 + c5;
#pragma unroll
      for (int q = 0; q < 4; ++q) {
        bf16x4 hv;
#pragma unroll
        for (int i = 0; i < 4; ++i)
          hv[i] = (bf16)fmaxf(acc[nt][4 * q + i] + bb[q][i], 0.0f);
        *reinterpret_cast<bf16x4*>(&hbuf[t * CSTR + w * 32 + 8 * q + 4 * hi]) = hv;
      }
    }
  }
  __syncthreads();   // B1: h_mid visible

  // ---- 4. GEMM3: H2 = Wl1^T x H1 (B-frag: 8 contiguous channels at fixed t) ----
#pragma unroll
  for (int nt = 0; nt < 4; ++nt) acc[nt] = (f32x16){};
#pragma unroll
  for (int kt = 0; kt < 16; ++kt) {
    const bf16x8 a = *reinterpret_cast<const bf16x8*>(
        ws + PWL1_OFF + (size_t)(kt * 8 + w) * 512 + lane * 8);
    const int koff = kt * 16 + hi * 8;
#pragma unroll
    for (int nt = 0; nt < 4; ++nt) {
      const bf16x8 b = *reinterpret_cast<const bf16x8*>(
          &hbuf[(nt * 32 + c5) * CSTR + koff]);
      acc[nt] = __builtin_amdgcn_mfma_f32_32x32x16_bf16(a, b, acc[nt], 0, 0, 0);
    }
  }

  // ---- 4b. mu_mid = W2^T x H1: wave w owns t-tile w (t = w*16 + m) ----
  f32x4 mu = {0.f, 0.f, 0.f, 0.f};
#pragma unroll
  for (int kt = 0; kt < 8; ++kt) {
    const bf16x8 a = *reinterpret_cast<const bf16x8*>(
        ws + PW2_OFF + (size_t)kt * 512 + lane * 8);
    const bf16x8 b = *reinterpret_cast<const bf16x8*>(
        &hbuf[(w * 16 + m) * CSTR + kt * 32 + g * 8]);
    mu = __builtin_amdgcn_mfma_f32_16x16x32_bf16(a, b, mu, 0, 0, 0);
  }
  {
    // D: col=t (m), row=channel g*4+j -> lanes g==0 hold channels 0..3.
    const long t = t0 + w * 16 + m;
    if (g == 0 && t < T_DATA) {
      const f32x4 b2v = *reinterpret_cast<const f32x4*>(b2);
      f32x4 o;
#pragma unroll
      for (int j = 0; j < 4; ++j) o[j] = mu[j] + b2v[j];
      *reinterpret_cast<f32x4*>(&out[t * 20]) = o;   // one dwordx4 store
    }
  }
  __syncthreads();   // B2 (WAR): all h_mid reads done before h_leaf overwrite

  // ---- 5. h_leaf epilogue: packed b64 writes ----
  {
    f32x4 bb[4];
#pragma unroll
    for (int q = 0; q < 4; ++q)
      bb[q] = *reinterpret_cast<const f32x4*>(&bl1[w * 32 + 8 * q + 4 * hi]);
#pragma unroll
    for (int nt = 0; nt < 4; ++nt) {
      const int t = nt * 32 + c5;
#pragma unroll
      for (int q = 0; q < 4; ++q) {
        bf16x4 hv;
#pragma unroll
        for (int i = 0; i < 4; ++i)
          hv[i] = (bf16)fmaxf(acc[nt][4 * q + i] + bb[q][i], 0.0f);
        *reinterpret_cast<bf16x4*>(&hbuf[t * CSTR + w * 32 + 8 * q + 4 * hi]) = hv;
      }
    }
  }
  __syncthreads();   // B3: h_leaf visible

  // ---- 6. mu_leaf = Wl2^T x H2: one dwordx4 store per lane ----
  mu = (f32x4){0.f, 0.f, 0.f, 0.f};
#pragma unroll
  for (int kq = 0; kq < 8; ++kq) {
    const bf16x8 a = *reinterpret_cast<const bf16x8*>(
        ws + PWL2_OFF + (size_t)kq * 512 + lane * 8);
    const bf16x8 b = *reinterpret_cast<const bf16x8*>(
        &hbuf[(w * 16 + m) * CSTR + kq * 32 + g * 8]);
    mu = __builtin_amdgcn_mfma_f32_16x16x32_bf16(a, b, mu, 0, 0, 0);
  }
  {
    const long t = t0 + w * 16 + m;
    if (t < T_DATA) {
      const f32x4 blv = *reinterpret_cast<const f32x4*>(&bl2[g * 4]);
      f32x4 o;
#pragma unroll
      for (int j = 0; j < 4; ++j) o[j] = mu[j] + blv[j];
      *reinterpret_cast<f32x4*>(&out[t * 20 + 4 + g * 4]) = o;  // 16B-aligned
    }
  }
}

extern "C" void kernel_launch(void* const* d_in, const int* in_sizes, int n_in,
                              void* d_out, int out_size, void* d_ws, size_t ws_size,
                              hipStream_t stream) {
  const float* V   = (const float*)d_in[0];
  const float* W1  = (const float*)d_in[1];
  const float* b1  = (const float*)d_in[2];
  const float* W2  = (const float*)d_in[3];
  const float* b2  = (const float*)d_in[4];
  const float* Wl1 = (const float*)d_in[5];
  const float* bl1 = (const float*)d_in[6];
  const float* Wl2 = (const float*)d_in[7];
  const float* bl2 = (const float*)d_in[8];
  bf16* ws = (bf16*)d_ws;   // needs 253952 bytes
  float* out = (float*)d_out;

  pack_weights<<<62, 256, 0, stream>>>(W1, W2, Wl1, Wl2, ws);

  const int grid = (T_DATA + BT - 1) / BT;   // 782
  fused_enc<<<grid, 512, 0, stream>>>(V, b1, b2, bl1, bl2, ws, out);
}